// Round 9
// baseline (51.223 us; speedup 1.0000x reference)
//
#include <hip/hip_runtime.h>

// Problem constants (B=1): inputs (N=32768, D=1024) f32, tag_to_token (T=128, N) f32,
// gat_mask (T, T) i32. Output (T, D) f32.
#define NTOK 32768
#define NTAG 128
#define DDIM 1024
#define TPB 32  // tokens per fused block

// ws layout:
//   P     : 128*1024 f32 = 524288 B (unscaled per-tag sums)
//   cnt   : 128 i32      = 512 B
//   maskT : 32*16 u32    = 2048 B  (bit-transposed gm: word (k,iw), lane l,
//                                   bit ib = gm[iw*32+ib][16k+l])

// ---------------------------------------------------------------------------
// Kernel 0: zero P/cnt; blocks 1-2 additionally build the bit-transposed gm
// mask table as a 512-thread gather (thread (k,iw,l) reads 32 strided ints,
// fully unrolled -> all loads in flight, writes one word).
// ---------------------------------------------------------------------------
__global__ __launch_bounds__(256) void k_zero(const int* __restrict__ gm,
                                              float* __restrict__ P,
                                              int* __restrict__ cnt,
                                              unsigned* __restrict__ maskT) {
    const int tid = threadIdx.x;
    const int gid = blockIdx.x * 256 + tid;
    reinterpret_cast<float4*>(P)[gid] = make_float4(0.f, 0.f, 0.f, 0.f);
    if (gid < NTAG) cnt[gid] = 0;

    if (blockIdx.x == 1 || blockIdx.x == 2) {
        const int idx = (blockIdx.x - 1) * 256 + tid;  // 0..511 = (k*4+iw)*16+l
        const int l = idx & 15;
        const int iw = (idx >> 4) & 3;
        const int k = idx >> 6;
        const int colg = 16 * k + l;  // gm column this word tracks
        unsigned w = 0;
#pragma unroll
        for (int ib = 0; ib < 32; ++ib)
            w |= (unsigned)(gm[(iw * 32 + ib) * NTAG + colg] != 0) << ib;
        maskT[idx] = w;
    }
}

// ---------------------------------------------------------------------------
// Kernel 1: fused tag-scan + segmented sum (unchanged — near the HBM/L3
// streaming floor for its 144 MB). Math fact: deduce_direct_string's
// temp[i][n] is 1 iff i is the LAST covering tag of n (for ANY 0/1
// coverage), so the row-normalized t2t is one-hot per token / cnt[tag] ->
// the big matmul is a segmented sum into P[tag], scaled later by 1/cnt.
// ---------------------------------------------------------------------------
__global__ __launch_bounds__(256) void k_fused(const float* __restrict__ inp,
                                               const float* __restrict__ t2t,
                                               float* __restrict__ P,
                                               int* __restrict__ cnt) {
    __shared__ int part[8][TPB];
    __shared__ int tags[TPB];
    const int tid = threadIdx.x;
    const int n0 = blockIdx.x * TPB;

    {
        const int c = tid >> 5;  // row chunk (16 rows)
        const int n = tid & 31;  // token within block
        int m = -1;
#pragma unroll
        for (int j = 0; j < 16; ++j) {
            const int r = c * 16 + j;
            if (t2t[(size_t)r * NTOK + n0 + n] > 0.f) m = r;
        }
        part[c][n] = m;
    }
    __syncthreads();
    if (tid < TPB) {
        int m = -1;
#pragma unroll
        for (int cc = 0; cc < 8; ++cc) m = max(m, part[cc][tid]);
        tags[tid] = m;
    }
    __syncthreads();

    const int col = tid * 4;
    const float4* src = reinterpret_cast<const float4*>(inp) + (size_t)n0 * 256 + tid;

    float4 acc = make_float4(0.f, 0.f, 0.f, 0.f);
    int cur = tags[0];
    int runlen = 0;

#pragma unroll
    for (int half = 0; half < 2; ++half) {
        float4 v[16];
#pragma unroll
        for (int k = 0; k < 16; ++k)
            v[k] = src[(size_t)(half * 16 + k) * 256];  // 16 loads in flight
#pragma unroll
        for (int k = 0; k < 16; ++k) {
            const int tg = tags[half * 16 + k];
            if (tg != cur) {  // wave-uniform (tags uniform across lanes)
                if (cur >= 0) {
                    float* p = P + (size_t)cur * DDIM + col;
                    atomicAdd(p + 0, acc.x);
                    atomicAdd(p + 1, acc.y);
                    atomicAdd(p + 2, acc.z);
                    atomicAdd(p + 3, acc.w);
                    if (tid == 0) atomicAdd(&cnt[cur], runlen);
                }
                acc = make_float4(0.f, 0.f, 0.f, 0.f);
                cur = tg;
                runlen = 0;
            }
            if (tg >= 0) {
                acc.x += v[k].x;
                acc.y += v[k].y;
                acc.z += v[k].z;
                acc.w += v[k].w;
                ++runlen;
            }
        }
    }
    if (cur >= 0) {
        float* p = P + (size_t)cur * DDIM + col;
        atomicAdd(p + 0, acc.x);
        atomicAdd(p + 1, acc.y);
        atomicAdd(p + 2, acc.z);
        atomicAdd(p + 3, acc.w);
        if (tid == 0) atomicAdd(&cnt[cur], runlen);
    }
}

// ---------------------------------------------------------------------------
// Kernel 2: triangular recurrence, all-register. deduce_child(gm) == gm for
// ANY input (inner loop provably a no-op). o[i] = sum_t gm[i][t]*o_cur[t],
// i=127..0, independent per column d. One wave = 4 columns (16-lane groups);
// lane l of group g holds o[16k+l] (8 VGPRs); gm bits in 32 VGPRs from
// maskT. Per step: 8x shift/and/cvt/fmac + 4 DPP adds + 1 guarded move; no
// memory in the loop; ~6KB body.
//
// ROUND 9 FIX: __launch_bounds__(64, 1). Previous rounds' bare
// __launch_bounds__(64) let the allocator target high occupancy -> ~16 VGPRs
// -> mw[8][4]+o0..o7 spilled to scratch -> ~8 spill reads/step ~= 600cy/step
// (R6's VGPR_Count=16 was the smoking gun; R8's k_recur inferred ~32us).
// min-waves=1 lifts the budget to 512 VGPRs so the working set stays
// resident. Everything else unchanged (single-variable A/B).
// ---------------------------------------------------------------------------
template <int CTRL>
__device__ __forceinline__ float dpp_add(float x) {
    const int y = __builtin_amdgcn_update_dpp(0, __float_as_int(x), CTRL, 0xF, 0xF, true);
    return x + __int_as_float(y);
}

__global__ __launch_bounds__(64, 1) void k_recur(const float* __restrict__ P,
                                                 const unsigned* __restrict__ maskT,
                                                 const int* __restrict__ cnt,
                                                 float* __restrict__ out) {
    __shared__ float xpose[NTAG][5];  // padded: stride 5 coprime 32 banks
    const int L = threadIdx.x;  // 0..63
    const int g = L >> 4;       // column group
    const int l = L & 15;       // sublane (t-slot)
    const int c0 = blockIdx.x * 4;

    // 32 mask words per lane (static indices via full unroll of k,iw).
    unsigned mw[8][4];
#pragma unroll
    for (int k = 0; k < 8; ++k)
#pragma unroll
        for (int iw = 0; iw < 4; ++iw) mw[k][iw] = maskT[(k * 4 + iw) * 16 + l];

    // Load P rows L and 64+L, scale by 1/cnt, transpose via LDS.
    const float ia = 1.0f / (float)cnt[L];
    const float ib_ = 1.0f / (float)cnt[64 + L];
    float4 pa = *reinterpret_cast<const float4*>(P + (size_t)L * DDIM + c0);
    float4 pb = *reinterpret_cast<const float4*>(P + (size_t)(64 + L) * DDIM + c0);
    xpose[L][0] = pa.x * ia;
    xpose[L][1] = pa.y * ia;
    xpose[L][2] = pa.z * ia;
    xpose[L][3] = pa.w * ia;
    xpose[64 + L][0] = pb.x * ib_;
    xpose[64 + L][1] = pb.y * ib_;
    xpose[64 + L][2] = pb.z * ib_;
    xpose[64 + L][3] = pb.w * ib_;
    __syncthreads();

    float o0 = xpose[l][g], o1 = xpose[16 + l][g];
    float o2 = xpose[32 + l][g], o3 = xpose[48 + l][g];
    float o4 = xpose[64 + l][g], o5 = xpose[80 + l][g];
    float o6 = xpose[96 + l][g], o7 = xpose[112 + l][g];

    // Section: rows i = IW*32 + ib for ib in [IBLO, IBHI], update slot oKU
    // (KU = i>>4 constant per section; l == (ib & 15) picks the lane).
#define SECTION(IW, KU, IBHI, IBLO)                                         \
    _Pragma("unroll 2") for (int ib = IBHI; ib >= IBLO; --ib) {             \
        float sa = (float)((mw[0][IW] >> ib) & 1u) * o0;                    \
        sa += (float)((mw[1][IW] >> ib) & 1u) * o1;                         \
        sa += (float)((mw[2][IW] >> ib) & 1u) * o2;                         \
        sa += (float)((mw[3][IW] >> ib) & 1u) * o3;                         \
        float sb = (float)((mw[4][IW] >> ib) & 1u) * o4;                    \
        sb += (float)((mw[5][IW] >> ib) & 1u) * o5;                         \
        sb += (float)((mw[6][IW] >> ib) & 1u) * o6;                         \
        sb += (float)((mw[7][IW] >> ib) & 1u) * o7;                         \
        float s = sa + sb;                                                  \
        s = dpp_add<0xB1>(s);  /* quad_perm xor1 */                         \
        s = dpp_add<0x4E>(s);  /* quad_perm xor2 */                         \
        s = dpp_add<0x141>(s); /* row_half_mirror */                        \
        s = dpp_add<0x140>(s); /* row_mirror: 16-lane total in all lanes */ \
        if (l == (ib & 15)) o##KU = s;                                      \
    }

    SECTION(3, 7, 31, 16)
    SECTION(3, 6, 15, 0)
    SECTION(2, 5, 31, 16)
    SECTION(2, 4, 15, 0)
    SECTION(1, 3, 31, 16)
    SECTION(1, 2, 15, 0)
    SECTION(0, 1, 31, 16)
    SECTION(0, 0, 15, 0)
#undef SECTION

    // Transpose back through LDS, store coalesced float4 rows.
    __syncthreads();
    xpose[l][g] = o0;
    xpose[16 + l][g] = o1;
    xpose[32 + l][g] = o2;
    xpose[48 + l][g] = o3;
    xpose[64 + l][g] = o4;
    xpose[80 + l][g] = o5;
    xpose[96 + l][g] = o6;
    xpose[112 + l][g] = o7;
    __syncthreads();
    float4 ra, rb;
    ra.x = xpose[L][0];
    ra.y = xpose[L][1];
    ra.z = xpose[L][2];
    ra.w = xpose[L][3];
    rb.x = xpose[64 + L][0];
    rb.y = xpose[64 + L][1];
    rb.z = xpose[64 + L][2];
    rb.w = xpose[64 + L][3];
    *reinterpret_cast<float4*>(out + (size_t)L * DDIM + c0) = ra;
    *reinterpret_cast<float4*>(out + (size_t)(64 + L) * DDIM + c0) = rb;
}

// ---------------------------------------------------------------------------
extern "C" void kernel_launch(void* const* d_in, const int* in_sizes, int n_in,
                              void* d_out, int out_size, void* d_ws, size_t ws_size,
                              hipStream_t stream) {
    const float* inp = (const float*)d_in[0];  // (N, D)
    const float* t2t = (const float*)d_in[1];  // (T, N)
    const int* gm = (const int*)d_in[2];       // (T, T)
    float* out = (float*)d_out;                // (T, D)

    char* ws = (char*)d_ws;
    float* P = (float*)ws;                       // 524288 B
    int* cnt = (int*)(ws + 524288);              // 512 B
    unsigned* maskT = (unsigned*)(ws + 524800);  // 2048 B

    k_zero<<<128, 256, 0, stream>>>(gm, P, cnt, maskT);
    k_fused<<<NTOK / TPB, 256, 0, stream>>>(inp, t2t, P, cnt);
    k_recur<<<DDIM / 4, 64, 0, stream>>>(P, maskT, cnt, out);
}

// Round 10
// 51.031 us; speedup vs baseline: 1.0038x; 1.0038x over previous
//
#include <hip/hip_runtime.h>

// Problem constants (B=1): inputs (N=32768, D=1024) f32, tag_to_token (T=128, N) f32,
// gat_mask (T, T) i32. Output (T, D) f32.
#define NTOK 32768
#define NTAG 128
#define DDIM 1024
#define TPB 32  // tokens per fused block

// ws layout:
//   P   : 128*1024 f32 = 524288 B (unscaled per-tag sums)
//   cnt : 128 i32      = 512 B
//   RT  : 128*128 f32  = 65536 B  (fused-row table, lane-major per row:
//                                  RT[j*128 + l*8 + k] = rtilde_j[16k+l])

// ---------------------------------------------------------------------------
// Kernel 0 (k_rt): zero P/cnt + build the fused-row table RT.
// deduce_child(gm) == gm for ANY input (the reference inner loop is provably
// a no-op: rows j>i are still zero at outer step i). The recurrence
// o[i] = sum_t gm[i][t]*o_cur[t], i=127..0, is block-back-substituted in
// groups of 8 rows: rtilde_j = gm_j restricted to t outside (j, g0+8)
//                             + sum_{k in group, k>j} gm_j[k] * rtilde_k,
// so all 8 rows of a group are computable from the SAME pre-group state.
// Entries are exact small integers in f32. One block per group (16 blocks,
// 128 threads = one column each); serial depth 8 inside the block.
// ---------------------------------------------------------------------------
__global__ __launch_bounds__(128) void k_rt(const int* __restrict__ gm,
                                            float* __restrict__ P,
                                            int* __restrict__ cnt,
                                            float* __restrict__ RT) {
    __shared__ float rt[8][NTAG];
    __shared__ float gblk[8][8];
    const int t = threadIdx.x;   // column 0..127
    const int b = blockIdx.x;    // group 0..15
    const int g0 = b * 8;

    // Zero P (16 blocks x 128 threads x 16 float4 = 131072 floats) and cnt.
    float4* P4 = reinterpret_cast<float4*>(P) + b * 2048 + t;
#pragma unroll
    for (int q = 0; q < 16; ++q) P4[q * 128] = make_float4(0.f, 0.f, 0.f, 0.f);
    if (b == 0) cnt[t] = 0;

    // In-group 8x8 adjacency + this thread's column of the 8 base rows.
    if (t < 64) gblk[t >> 3][t & 7] =
        (float)(gm[(g0 + (t >> 3)) * NTAG + g0 + (t & 7)] != 0);
    float grows[8];
#pragma unroll
    for (int jj = 0; jj < 8; ++jj)
        grows[jj] = (float)(gm[(g0 + jj) * NTAG + t] != 0);
    __syncthreads();

#pragma unroll
    for (int jj = 7; jj >= 0; --jj) {
        const int j = g0 + jj;
        // base: keep t<=j and t>=g0+8 (outside the not-yet-updated span)
        float acc = (t > j && t < g0 + 8) ? 0.f : grows[jj];
        for (int k = jj + 1; k < 8; ++k) acc += gblk[jj][k] * rt[k][t];
        rt[jj][t] = acc;
        __syncthreads();
    }

    // Store lane-major: RT[j][l*8 + k] = rtilde_j[16k+l]  (t = 16k+l).
#pragma unroll
    for (int jj = 0; jj < 8; ++jj)
        RT[(g0 + jj) * NTAG + (t & 15) * 8 + (t >> 4)] = rt[jj][t];
}

// ---------------------------------------------------------------------------
// Kernel 1: fused tag-scan + segmented sum (unchanged — ~15-16us, near the
// streaming floor for its 144 MB). Math fact: deduce_direct_string's
// temp[i][n] is 1 iff i is the LAST covering tag of n (for ANY 0/1
// coverage), so the row-normalized t2t is one-hot per token / cnt[tag] ->
// the big matmul is a segmented sum into P[tag], scaled later by 1/cnt.
// ---------------------------------------------------------------------------
__global__ __launch_bounds__(256) void k_fused(const float* __restrict__ inp,
                                               const float* __restrict__ t2t,
                                               float* __restrict__ P,
                                               int* __restrict__ cnt) {
    __shared__ int part[8][TPB];
    __shared__ int tags[TPB];
    const int tid = threadIdx.x;
    const int n0 = blockIdx.x * TPB;

    {
        const int c = tid >> 5;  // row chunk (16 rows)
        const int n = tid & 31;  // token within block
        int m = -1;
#pragma unroll
        for (int j = 0; j < 16; ++j) {
            const int r = c * 16 + j;
            if (t2t[(size_t)r * NTOK + n0 + n] > 0.f) m = r;
        }
        part[c][n] = m;
    }
    __syncthreads();
    if (tid < TPB) {
        int m = -1;
#pragma unroll
        for (int cc = 0; cc < 8; ++cc) m = max(m, part[cc][tid]);
        tags[tid] = m;
    }
    __syncthreads();

    const int col = tid * 4;
    const float4* src = reinterpret_cast<const float4*>(inp) + (size_t)n0 * 256 + tid;

    float4 acc = make_float4(0.f, 0.f, 0.f, 0.f);
    int cur = tags[0];
    int runlen = 0;

#pragma unroll
    for (int half = 0; half < 2; ++half) {
        float4 v[16];
#pragma unroll
        for (int k = 0; k < 16; ++k)
            v[k] = src[(size_t)(half * 16 + k) * 256];  // 16 loads in flight
#pragma unroll
        for (int k = 0; k < 16; ++k) {
            const int tg = tags[half * 16 + k];
            if (tg != cur) {  // wave-uniform (tags uniform across lanes)
                if (cur >= 0) {
                    float* p = P + (size_t)cur * DDIM + col;
                    atomicAdd(p + 0, acc.x);
                    atomicAdd(p + 1, acc.y);
                    atomicAdd(p + 2, acc.z);
                    atomicAdd(p + 3, acc.w);
                    if (tid == 0) atomicAdd(&cnt[cur], runlen);
                }
                acc = make_float4(0.f, 0.f, 0.f, 0.f);
                cur = tg;
                runlen = 0;
            }
            if (tg >= 0) {
                acc.x += v[k].x;
                acc.y += v[k].y;
                acc.z += v[k].z;
                acc.w += v[k].w;
                ++runlen;
            }
        }
    }
    if (cur >= 0) {
        float* p = P + (size_t)cur * DDIM + col;
        atomicAdd(p + 0, acc.x);
        atomicAdd(p + 1, acc.y);
        atomicAdd(p + 2, acc.z);
        atomicAdd(p + 3, acc.w);
        if (tid == 0) atomicAdd(&cnt[cur], runlen);
    }
}

// ---------------------------------------------------------------------------
// Kernel 2: recurrence apply with 8-row fused groups. One wave = 4 columns
// (16-lane groups); lane l of group g holds o[16k+l] in o0..o7 for column
// c0+g. Per group (16 groups, descending): 16 independent float4 loads of
// rtilde (prefetchable, L2-hot 64KB), then 8 INDEPENDENT dot+DPP chains
// (their dependency stalls overlap 8x -- this is the fix for the persistent
// ~610cy/step serial chain of rounds 5-9), then 8 guarded updates into ONE
// o-slot. Serial depth: 16 fused steps instead of 128.
// ---------------------------------------------------------------------------
template <int CTRL>
__device__ __forceinline__ float dpp_add(float x) {
    const int y = __builtin_amdgcn_update_dpp(0, __float_as_int(x), CTRL, 0xF, 0xF, true);
    return x + __int_as_float(y);
}

__global__ __launch_bounds__(64, 1) void k_recur(const float* __restrict__ P,
                                                 const float* __restrict__ RT,
                                                 const int* __restrict__ cnt,
                                                 float* __restrict__ out) {
    __shared__ float xpose[NTAG][5];  // padded transpose buffer
    const int L = threadIdx.x;  // 0..63
    const int g = L >> 4;       // column group
    const int l = L & 15;       // sublane (t mod 16)
    const int c0 = blockIdx.x * 4;

    // Load P rows L and 64+L, scale by 1/cnt, transpose via LDS.
    const float ia = 1.0f / (float)cnt[L];
    const float ib_ = 1.0f / (float)cnt[64 + L];
    float4 pa = *reinterpret_cast<const float4*>(P + (size_t)L * DDIM + c0);
    float4 pb = *reinterpret_cast<const float4*>(P + (size_t)(64 + L) * DDIM + c0);
    xpose[L][0] = pa.x * ia;
    xpose[L][1] = pa.y * ia;
    xpose[L][2] = pa.z * ia;
    xpose[L][3] = pa.w * ia;
    xpose[64 + L][0] = pb.x * ib_;
    xpose[64 + L][1] = pb.y * ib_;
    xpose[64 + L][2] = pb.z * ib_;
    xpose[64 + L][3] = pb.w * ib_;
    __syncthreads();

    float o0 = xpose[l][g], o1 = xpose[16 + l][g];
    float o2 = xpose[32 + l][g], o3 = xpose[48 + l][g];
    float o4 = xpose[64 + l][g], o5 = xpose[80 + l][g];
    float o6 = xpose[96 + l][g], o7 = xpose[112 + l][g];

    // Section KU handles groups G=2KU+1 (rows 16KU+8..+15) then G=2KU
    // (rows 16KU..+7), both updating slot oKU. All 8 dots of a group read
    // the pre-group o (SSA dataflow guarantees order).
#define GROUP_SECTION(KU)                                                      \
    for (int it = 1; it >= 0; --it) {                                          \
        const int jbase = KU * 16 + it * 8;                                    \
        const int lbase = it * 8;                                              \
        float4 ra[8], rb[8];                                                   \
        _Pragma("unroll") for (int jj = 0; jj < 8; ++jj) {                     \
            const float* rp = RT + (jbase + jj) * NTAG + l * 8;                \
            ra[jj] = *reinterpret_cast<const float4*>(rp);                     \
            rb[jj] = *reinterpret_cast<const float4*>(rp + 4);                 \
        }                                                                      \
        float s[8];                                                            \
        _Pragma("unroll") for (int jj = 0; jj < 8; ++jj) {                     \
            float sa = ra[jj].x * o0 + ra[jj].y * o1 + ra[jj].z * o2 +         \
                       ra[jj].w * o3;                                          \
            float sb = rb[jj].x * o4 + rb[jj].y * o5 + rb[jj].z * o6 +         \
                       rb[jj].w * o7;                                          \
            float ss = sa + sb;                                                \
            ss = dpp_add<0xB1>(ss);  /* quad_perm xor1 */                      \
            ss = dpp_add<0x4E>(ss);  /* quad_perm xor2 */                      \
            ss = dpp_add<0x141>(ss); /* row_half_mirror */                     \
            ss = dpp_add<0x140>(ss); /* row_mirror: 16-lane total */           \
            s[jj] = ss;                                                        \
        }                                                                      \
        _Pragma("unroll") for (int jj = 0; jj < 8; ++jj)                       \
            if (l == lbase + jj) o##KU = s[jj];                                \
    }

    GROUP_SECTION(7)
    GROUP_SECTION(6)
    GROUP_SECTION(5)
    GROUP_SECTION(4)
    GROUP_SECTION(3)
    GROUP_SECTION(2)
    GROUP_SECTION(1)
    GROUP_SECTION(0)
#undef GROUP_SECTION

    // Transpose back through LDS, store coalesced float4 rows.
    __syncthreads();
    xpose[l][g] = o0;
    xpose[16 + l][g] = o1;
    xpose[32 + l][g] = o2;
    xpose[48 + l][g] = o3;
    xpose[64 + l][g] = o4;
    xpose[80 + l][g] = o5;
    xpose[96 + l][g] = o6;
    xpose[112 + l][g] = o7;
    __syncthreads();
    float4 ra, rb;
    ra.x = xpose[L][0];
    ra.y = xpose[L][1];
    ra.z = xpose[L][2];
    ra.w = xpose[L][3];
    rb.x = xpose[64 + L][0];
    rb.y = xpose[64 + L][1];
    rb.z = xpose[64 + L][2];
    rb.w = xpose[64 + L][3];
    *reinterpret_cast<float4*>(out + (size_t)L * DDIM + c0) = ra;
    *reinterpret_cast<float4*>(out + (size_t)(64 + L) * DDIM + c0) = rb;
}

// ---------------------------------------------------------------------------
extern "C" void kernel_launch(void* const* d_in, const int* in_sizes, int n_in,
                              void* d_out, int out_size, void* d_ws, size_t ws_size,
                              hipStream_t stream) {
    const float* inp = (const float*)d_in[0];  // (N, D)
    const float* t2t = (const float*)d_in[1];  // (T, N)
    const int* gm = (const int*)d_in[2];       // (T, T)
    float* out = (float*)d_out;                // (T, D)

    char* ws = (char*)d_ws;
    float* P = (float*)ws;                  // 524288 B
    int* cnt = (int*)(ws + 524288);         // 512 B
    float* RT = (float*)(ws + 524800);      // 65536 B

    k_rt<<<16, 128, 0, stream>>>(gm, P, cnt, RT);
    k_fused<<<NTOK / TPB, 256, 0, stream>>>(inp, t2t, P, cnt);
    k_recur<<<DDIM / 4, 64, 0, stream>>>(P, RT, cnt, out);
}